// Round 1
// baseline (346.063 us; speedup 1.0000x reference)
//
#include <hip/hip_runtime.h>

// out = (I + W + W^2 + ... + W^max_steps) x, where W = 15-tap zero-padded
// correlation along the 256-channel axis. We build the composite 256x256
// banded matrix M on-device each launch (d_ws is re-poisoned), then apply it
// as a banded matvec over all 32*56*56 spatial columns.

#define SCOPE 15
#define PAD 7
#define NCH 256
#define SPATIAL 3136      // 56*56
#define PER_B 802816      // 256*3136
#define TS 64             // spatial columns per block

// ---- Kernel 1: build M (column d per block) ------------------------------
__global__ void build_M_kernel(const float* __restrict__ w,
                               const int* __restrict__ max_steps_p,
                               float* __restrict__ M) {
    const int d = blockIdx.x;   // column of M (input channel)
    const int c = threadIdx.x;  // row of M (output channel)
    __shared__ float v[2][NCH];
    __shared__ float wsh[SCOPE];
    if (c < SCOPE) wsh[c] = w[c];
    const float e = (c == d) ? 1.0f : 0.0f;
    v[0][c] = e;
    __syncthreads();
    const int steps = *max_steps_p;
    int cur = 0;
    for (int t = 0; t < steps; ++t) {
        float s = e;  // state = x + conv(state); here x = e_d
#pragma unroll
        for (int j = 0; j < SCOPE; ++j) {
            const int cc = c + j - PAD;
            if (cc >= 0 && cc < NCH) s += wsh[j] * v[cur][cc];
        }
        cur ^= 1;
        v[cur][c] = s;
        __syncthreads();
    }
    M[c * NCH + d] = v[cur][c];
}

// ---- Kernel 2: out[b,c,s] = sum_d M[c,d] * x[b,d,s] ----------------------
// Block: 512 threads (8 waves), one (b, 64-wide spatial tile).
// LDS: full 256-channel x 64-spatial fp32 tile (64 KB) -> 2 blocks/CU.
// Wave-uniform 8-row output tiles => coefficient loads are scalar (s_load),
// LDS reads are bank = lane%32 (free 2-way conflict).
__global__ __launch_bounds__(512, 4) void apply_M_kernel(
    const float* __restrict__ x, const float* __restrict__ M,
    float* __restrict__ out) {
    __shared__ float xs[NCH * TS];  // [c][s], 64 KB
    const int tid = threadIdx.x;
    const int s0 = blockIdx.x * TS;
    const int b = blockIdx.y;
    const size_t ibase = (size_t)b * PER_B + (size_t)s0;

    // Stage tile: 256 ch x 64 s = 4096 float4, 8 per thread, coalesced.
#pragma unroll
    for (int it = 0; it < 8; ++it) {
        const int flat4 = it * 512 + tid;     // 0..4095
        const int c = flat4 >> 4;             // 16 float4 per channel row
        const int sq = (flat4 & 15) << 2;
        const float4 vv = *(const float4*)(x + ibase + (size_t)c * SPATIAL + sq);
        *(float4*)(xs + c * TS + sq) = vv;
    }
    __syncthreads();

    const int lane = tid & 63;
    const int wave = __builtin_amdgcn_readfirstlane(tid >> 6);  // wave-uniform

    for (int pass = 0; pass < 4; ++pass) {
        const int c0 = (pass * 8 + wave) * 8;  // 8-row output tile, uniform
        int dlo = c0 - 70;
        if (dlo < 0) dlo = 0;
        dlo &= ~3;                 // 4-aligned => float4 reads stay in-row
        int dhi = c0 + 7 + 70;
        if (dhi > NCH - 1) dhi = NCH - 1;

        float acc[8];
#pragma unroll
        for (int i = 0; i < 8; ++i) acc[i] = 0.0f;

        for (int d = dlo; d <= dhi; d += 4) {
            const float x0 = xs[(d + 0) * TS + lane];
            const float x1 = xs[(d + 1) * TS + lane];
            const float x2 = xs[(d + 2) * TS + lane];
            const float x3 = xs[(d + 3) * TS + lane];
#pragma unroll
            for (int i = 0; i < 8; ++i) {
                const float4 cf = *(const float4*)(M + (size_t)(c0 + i) * NCH + d);
                acc[i] = fmaf(cf.x, x0, acc[i]);
                acc[i] = fmaf(cf.y, x1, acc[i]);
                acc[i] = fmaf(cf.z, x2, acc[i]);
                acc[i] = fmaf(cf.w, x3, acc[i]);
            }
        }

        float* op = out + ibase + (size_t)c0 * SPATIAL + lane;
#pragma unroll
        for (int i = 0; i < 8; ++i) op[(size_t)i * SPATIAL] = acc[i];
    }
}

extern "C" void kernel_launch(void* const* d_in, const int* in_sizes, int n_in,
                              void* d_out, int out_size, void* d_ws, size_t ws_size,
                              hipStream_t stream) {
    const float* x = (const float*)d_in[0];   // (32, 256, 56, 56) fp32
    const float* w = (const float*)d_in[1];   // (15,) fp32
    const int* ms = (const int*)d_in[2];      // scalar int (10)
    float* out = (float*)d_out;               // (32, 256, 56, 56) fp32
    float* M = (float*)d_ws;                  // 256*256 fp32 = 256 KB scratch

    build_M_kernel<<<256, NCH, 0, stream>>>(w, ms, M);
    apply_M_kernel<<<dim3(SPATIAL / TS, 32), 512, 0, stream>>>(x, M, out);
}

// Round 3
// 206.927 us; speedup vs baseline: 1.6724x; 1.6724x over previous
//
#include <hip/hip_runtime.h>

// out = (I + W + ... + W^10) x  ==  M . x   (M is 256x256, exactly banded +-70)
// Kernel 1: build M per column, emit split-precision bf16 Mh/Ml (row-major).
// Kernel 2: banded MFMA GEMM, A-frags register-resident, double-buffered
//           global_load_lds staging of fp32 x tiles, in-register bf16 split of x.

#define NCH 256
#define PAD 7
#define SCOPE 15
#define SPATIAL 3136
#define PER_B 802816          // 256*3136
#define STW 32                // spatial tile width
#define STILES_PER_B 98       // 3136/32
#define GRID_APPLY 224
#define NITER 14              // 224*14 = 3136 tiles = 32 batches * 98
#define MAXCH 12              // K-chunks (of 16) per 32-row band window

typedef __attribute__((ext_vector_type(8))) __bf16 bf16x8;
typedef __attribute__((ext_vector_type(16))) float float16;
typedef __attribute__((ext_vector_type(4))) unsigned int uint4v;

static __device__ __forceinline__ unsigned short f2bf_rn_u(float f) {
  unsigned u = __builtin_bit_cast(unsigned int, f);
  return (unsigned short)((u + 0x7FFFu + ((u >> 16) & 1u)) >> 16);
}
static __device__ __forceinline__ float bf2f_u(unsigned short h) {
  unsigned u = ((unsigned)h) << 16;
  return __builtin_bit_cast(float, u);
}
// pack two fp32 -> two bf16 (RNE) in one u32: a in low 16, b in high 16
static __device__ __forceinline__ unsigned pack_bf2(float a, float b) {
  return (unsigned)f2bf_rn_u(a) | ((unsigned)f2bf_rn_u(b) << 16);
}

// ---- Kernel 1: build M column d (block d), write bf16 hi/lo row-major ----
__global__ void build_M_kernel(const float* __restrict__ w,
                               const int* __restrict__ max_steps_p,
                               unsigned short* __restrict__ Mh,
                               unsigned short* __restrict__ Ml) {
  const int d = blockIdx.x;
  const int c = threadIdx.x;
  __shared__ float v[2][NCH];
  __shared__ float wsh[SCOPE];
  if (c < SCOPE) wsh[c] = w[c];
  const float e = (c == d) ? 1.0f : 0.0f;
  v[0][c] = e;
  __syncthreads();
  const int steps = *max_steps_p;
  int cur = 0;
  for (int t = 0; t < steps; ++t) {
    float s = e;
#pragma unroll
    for (int j = 0; j < SCOPE; ++j) {
      const int cc = c + j - PAD;
      if (cc >= 0 && cc < NCH) s += wsh[j] * v[cur][cc];
    }
    cur ^= 1;
    v[cur][c] = s;
    __syncthreads();
  }
  const float f = v[cur][c];
  const unsigned short h = f2bf_rn_u(f);
  Mh[c * NCH + d] = h;
  Ml[c * NCH + d] = f2bf_rn_u(f - bf2f_u(h));
}

// ---- Kernel 2: banded split-precision MFMA matvec over all spatial cols ----
// Block: 512 threads (8 waves). Wave w owns output channels [32w, 32w+32).
// A-frags (Mh/Ml, 12 chunks of K=16) preloaded once, persist over s-loop.
// Per iteration: one (batch, 32-wide spatial) tile; x staged fp32 via
// global_load_lds (double-buffered); B-frags = bf16 hi/lo built in-register.
__global__ __launch_bounds__(512, 2) void apply_M_kernel(
    const float* __restrict__ x, const unsigned short* __restrict__ Mh,
    const unsigned short* __restrict__ Ml, float* __restrict__ out) {
  __shared__ float tile[2][NCH * STW];  // 2 x 32 KB

  const int tid  = threadIdx.x;
  const int lane = tid & 63;
  const int w    = tid >> 6;   // wave 0..7
  const int m    = lane & 31;  // A row within c-tile == B spatial col
  const int half = lane >> 5;  // k-half (0: k 0..7, 1: k 8..15)
  const int c0   = w * 32;

  // band window [c0-70, c0+31+70] -> 12 chunks of 16 starting at tlo
  int tlo = c0 - 70;
  if (tlo < 0) tlo = 0;
  tlo >>= 4;
  if (tlo > 4) tlo = 4;  // keep tlo+11 <= 15 (extra chunks hit exact zeros in M)

  // ---- preload A fragments (persist across the whole s-loop) ----
  bf16x8 Ah[MAXCH], Al[MAXCH];
  {
    const int abase = (c0 + m) * NCH + half * 8;
#pragma unroll
    for (int i = 0; i < MAXCH; ++i) {
      const int off = abase + (tlo + i) * 16;
      Ah[i] = *(const bf16x8*)(Mh + off);
      Al[i] = *(const bf16x8*)(Ml + off);
    }
  }

  const int srow = lane >> 3;       // 0..7   (8 rows per load instruction)
  const int scol = (lane & 7) * 4;  // 0..28  (16B per lane along s)

  int tau = (int)blockIdx.x;
  int b   = tau / STILES_PER_B;
  int s0  = (tau % STILES_PER_B) * STW;

  // prologue: stage first tile into buffer 0 (wave w stages rows [32w,32w+32))
  {
    const float* gb = x + (size_t)b * PER_B + (size_t)s0;
#pragma unroll
    for (int r = 0; r < 4; ++r) {
      const int d0 = w * 32 + r * 8;
      const float* g = gb + (size_t)(d0 + srow) * SPATIAL + scol;
      __builtin_amdgcn_global_load_lds(
          (const __attribute__((address_space(1))) unsigned int*)g,
          (__attribute__((address_space(3))) unsigned int*)&tile[0][d0 * STW],
          16, 0, 0);
    }
  }

#pragma unroll 1
  for (int it = 0; it < NITER; ++it) {
    const int cur  = it & 1;
    const int more = (it + 1 < NITER) ? 1 : 0;
    const int ntau = tau + GRID_APPLY;
    const int nb   = more ? (ntau / STILES_PER_B) : 0;
    const int ns0  = more ? (ntau % STILES_PER_B) * STW : 0;

    __syncthreads();  // my stage loads drained; all waves done with other buffer

    if (more) {  // issue next tile's staging into the other buffer (no wait)
      const float* gb = x + (size_t)nb * PER_B + (size_t)ns0;
#pragma unroll
      for (int r = 0; r < 4; ++r) {
        const int d0 = w * 32 + r * 8;
        const float* g = gb + (size_t)(d0 + srow) * SPATIAL + scol;
        __builtin_amdgcn_global_load_lds(
            (const __attribute__((address_space(1))) unsigned int*)g,
            (__attribute__((address_space(3))) unsigned int*)&tile[1 - cur][d0 * STW],
            16, 0, 0);
      }
    }

    const float* tb = &tile[cur][0];
    float16 acc;
#pragma unroll
    for (int q = 0; q < 16; ++q) acc[q] = 0.0f;

#pragma unroll
    for (int i = 0; i < MAXCH; ++i) {
      const int dk = (tlo + i) * 16 + half * 8;
      const float* p = tb + dk * STW + m;  // lanes n hit all 32 banks: conflict-free
      const float v0 = p[0 * STW], v1 = p[1 * STW], v2 = p[2 * STW],
                  v3 = p[3 * STW], v4 = p[4 * STW], v5 = p[5 * STW],
                  v6 = p[6 * STW], v7 = p[7 * STW];

      const unsigned uh0 = pack_bf2(v0, v1);
      const unsigned uh1 = pack_bf2(v2, v3);
      const unsigned uh2 = pack_bf2(v4, v5);
      const unsigned uh3 = pack_bf2(v6, v7);

      const float r0 = v0 - __builtin_bit_cast(float, uh0 << 16);
      const float r1 = v1 - __builtin_bit_cast(float, uh0 & 0xFFFF0000u);
      const float r2 = v2 - __builtin_bit_cast(float, uh1 << 16);
      const float r3 = v3 - __builtin_bit_cast(float, uh1 & 0xFFFF0000u);
      const float r4 = v4 - __builtin_bit_cast(float, uh2 << 16);
      const float r5 = v5 - __builtin_bit_cast(float, uh2 & 0xFFFF0000u);
      const float r6 = v6 - __builtin_bit_cast(float, uh3 << 16);
      const float r7 = v7 - __builtin_bit_cast(float, uh3 & 0xFFFF0000u);

      const unsigned ul0 = pack_bf2(r0, r1);
      const unsigned ul1 = pack_bf2(r2, r3);
      const unsigned ul2 = pack_bf2(r4, r5);
      const unsigned ul3 = pack_bf2(r6, r7);

      const uint4v vh = {uh0, uh1, uh2, uh3};
      const uint4v vl = {ul0, ul1, ul2, ul3};
      const bf16x8 bh = __builtin_bit_cast(bf16x8, vh);
      const bf16x8 bl = __builtin_bit_cast(bf16x8, vl);

      acc = __builtin_amdgcn_mfma_f32_32x32x16_bf16(Ah[i], bh, acc, 0, 0, 0);
      acc = __builtin_amdgcn_mfma_f32_32x32x16_bf16(Ah[i], bl, acc, 0, 0, 0);
      acc = __builtin_amdgcn_mfma_f32_32x32x16_bf16(Al[i], bh, acc, 0, 0, 0);
    }

    // epilogue: C/D map (32x32): col = lane&31, row = (r&3) + 8*(r>>2) + 4*half
    float* ob = out + (size_t)b * PER_B + (size_t)s0 + m;
#pragma unroll
    for (int r = 0; r < 16; ++r) {
      const int row = (r & 3) + 8 * (r >> 2) + 4 * half;
      ob[(size_t)(c0 + row) * SPATIAL] = acc[r];
    }

    tau = ntau;
    b = nb;
    s0 = ns0;
  }
}

extern "C" void kernel_launch(void* const* d_in, const int* in_sizes, int n_in,
                              void* d_out, int out_size, void* d_ws, size_t ws_size,
                              hipStream_t stream) {
  const float* x = (const float*)d_in[0];  // (32, 256, 56, 56) fp32
  const float* w = (const float*)d_in[1];  // (15,) fp32
  const int* ms = (const int*)d_in[2];     // scalar int (10)
  float* out = (float*)d_out;              // (32, 256, 56, 56) fp32

  unsigned short* Mh = (unsigned short*)d_ws;   // 128 KB
  unsigned short* Ml = Mh + NCH * NCH;          // 128 KB

  build_M_kernel<<<NCH, NCH, 0, stream>>>(w, ms, Mh, Ml);
  apply_M_kernel<<<GRID_APPLY, 512, 0, stream>>>(x, Mh, Ml, out);
}

// Round 4
// 205.074 us; speedup vs baseline: 1.6875x; 1.0090x over previous
//
#include <hip/hip_runtime.h>

// out = (I + W + ... + W^10) x == M . x  (M 256x256, exactly banded +-70).
// K1: build M per column, split-precision bf16 Mh/Ml (row-major).
// K2: banded MFMA GEMM. Per 32-wide spatial tile: register-prefetched float4
//     loads -> one cooperative bf16 hi/lo split -> LDS in B-frag word layout
//     ([k/2][n] packed pairs) -> per-wave banded MFMA with zero-chunk skip.

#define NCH 256
#define PAD 7
#define SCOPE 15
#define SPATIAL 3136
#define PER_B 802816          // 256*3136
#define STW 32                // spatial tile width
#define STILES_PER_B 98       // 3136/32
#define NTILES 3136           // 32*98
#define GRID_APPLY 256
#define MAXCH 12              // max K-chunks (of 16) per wave band window

typedef __attribute__((ext_vector_type(8))) __bf16 bf16x8;
typedef __attribute__((ext_vector_type(16))) float float16;
typedef __attribute__((ext_vector_type(4))) unsigned int uint4v;

static __device__ __forceinline__ unsigned short f2bf_rn_u(float f) {
  unsigned u = __builtin_bit_cast(unsigned int, f);
  return (unsigned short)((u + 0x7FFFu + ((u >> 16) & 1u)) >> 16);
}
static __device__ __forceinline__ float bf2f_u(unsigned short h) {
  unsigned u = ((unsigned)h) << 16;
  return __builtin_bit_cast(float, u);
}
static __device__ __forceinline__ unsigned pack_bf2(float a, float b) {
  return (unsigned)f2bf_rn_u(a) | ((unsigned)f2bf_rn_u(b) << 16);
}
// split floats (a,b) -> hi packed word + lo (residual) packed word
static __device__ __forceinline__ void split2(float a, float b,
                                              unsigned& h, unsigned& l) {
  h = pack_bf2(a, b);
  const float ra = a - __builtin_bit_cast(float, h << 16);
  const float rb = b - __builtin_bit_cast(float, h & 0xFFFF0000u);
  l = pack_bf2(ra, rb);
}

// ---- Kernel 1: build M column d (block d), write bf16 hi/lo row-major ----
__global__ void build_M_kernel(const float* __restrict__ w,
                               const int* __restrict__ max_steps_p,
                               unsigned short* __restrict__ Mh,
                               unsigned short* __restrict__ Ml) {
  const int d = blockIdx.x;
  const int c = threadIdx.x;
  __shared__ float v[2][NCH];
  __shared__ float wsh[SCOPE];
  if (c < SCOPE) wsh[c] = w[c];
  const float e = (c == d) ? 1.0f : 0.0f;
  v[0][c] = e;
  __syncthreads();
  const int steps = *max_steps_p;
  int cur = 0;
  for (int t = 0; t < steps; ++t) {
    float s = e;
#pragma unroll
    for (int j = 0; j < SCOPE; ++j) {
      const int cc = c + j - PAD;
      if (cc >= 0 && cc < NCH) s += wsh[j] * v[cur][cc];
    }
    cur ^= 1;
    v[cur][c] = s;
    __syncthreads();
  }
  const float f = v[cur][c];
  const unsigned short h = f2bf_rn_u(f);
  Mh[c * NCH + d] = h;
  Ml[c * NCH + d] = f2bf_rn_u(f - bf2f_u(h));
}

// ---- Kernel 2 -------------------------------------------------------------
// 512 threads (8 waves); wave w -> output channels [32w,32w+32).
// LDS: HB/LB = packed bf16-pair words, word (k2, n) = (bf16(x[2k2][n]),
// bf16(x[2k2+1][n])); B-frag = 4 ds_read_b32 stride 32 words (bank-free).
__global__ __launch_bounds__(512, 2) void apply_M_kernel(
    const float* __restrict__ x, const unsigned short* __restrict__ Mh,
    const unsigned short* __restrict__ Ml, float* __restrict__ out) {
  __shared__ unsigned HB[128 * STW];  // 16 KB
  __shared__ unsigned LB[128 * STW];  // 16 KB

  const int tid  = threadIdx.x;
  const int lane = tid & 63;
  const int w    = tid >> 6;
  const int m    = lane & 31;  // A row in c-tile == B spatial col
  const int half = lane >> 5;  // k-half
  const int c0   = w * 32;

  // exact nonzero band: rows [c0, c0+31] touch cols [c0-70, c0+101]
  int clo = c0 - 70; if (clo < 0) clo = 0; clo >>= 4;
  int chi = c0 + 101; if (chi > 255) chi = 255; chi >>= 4;
  const int nch = chi - clo + 1;  // 7..12 per wave

  bf16x8 Ah[MAXCH], Al[MAXCH];
#pragma unroll
  for (int i = 0; i < MAXCH; ++i) {
    if (i < nch) {
      const int off = (c0 + m) * NCH + (clo + i) * 16 + half * 8;
      Ah[i] = *(const bf16x8*)(Mh + off);
      Al[i] = *(const bf16x8*)(Ml + off);
    }
  }

  // loader geometry: thread -> (d-pair rows dg, dg+64; 4 spatial cols sq..sq+3)
  const int sq = (tid & 7) * 4;
  const int dg = tid >> 3;  // 0..63

  int tau = blockIdx.x;
  float4 g0, g1, g2, g3;
  {
    const float* gb = x + (size_t)(tau / STILES_PER_B) * PER_B
                        + (size_t)(tau % STILES_PER_B) * STW;
    g0 = *(const float4*)(gb + (size_t)(2 * dg) * SPATIAL + sq);
    g1 = *(const float4*)(gb + (size_t)(2 * dg + 1) * SPATIAL + sq);
    g2 = *(const float4*)(gb + (size_t)(2 * dg + 128) * SPATIAL + sq);
    g3 = *(const float4*)(gb + (size_t)(2 * dg + 129) * SPATIAL + sq);
  }

#pragma unroll 1
  for (; tau < NTILES; tau += GRID_APPLY) {
    __syncthreads();  // all waves done reading HB/LB from previous tile

    // cooperative split: registers -> bf16 hi/lo words in B-frag layout
    {
      unsigned h0, h1, h2, h3, l0, l1, l2, l3;
      split2(g0.x, g1.x, h0, l0); split2(g0.y, g1.y, h1, l1);
      split2(g0.z, g1.z, h2, l2); split2(g0.w, g1.w, h3, l3);
      *(uint4v*)&HB[dg * STW + sq] = (uint4v){h0, h1, h2, h3};
      *(uint4v*)&LB[dg * STW + sq] = (uint4v){l0, l1, l2, l3};
      split2(g2.x, g3.x, h0, l0); split2(g2.y, g3.y, h1, l1);
      split2(g2.z, g3.z, h2, l2); split2(g2.w, g3.w, h3, l3);
      *(uint4v*)&HB[(dg + 64) * STW + sq] = (uint4v){h0, h1, h2, h3};
      *(uint4v*)&LB[(dg + 64) * STW + sq] = (uint4v){l0, l1, l2, l3};
    }

    // prefetch next tile into registers (stays in flight across compute;
    // plain register loads are NOT drained by s_barrier)
    const int ntau = tau + GRID_APPLY;
    if (ntau < NTILES) {
      const float* gb = x + (size_t)(ntau / STILES_PER_B) * PER_B
                          + (size_t)(ntau % STILES_PER_B) * STW;
      g0 = *(const float4*)(gb + (size_t)(2 * dg) * SPATIAL + sq);
      g1 = *(const float4*)(gb + (size_t)(2 * dg + 1) * SPATIAL + sq);
      g2 = *(const float4*)(gb + (size_t)(2 * dg + 128) * SPATIAL + sq);
      g3 = *(const float4*)(gb + (size_t)(2 * dg + 129) * SPATIAL + sq);
    }

    __syncthreads();  // HB/LB complete

    // three independent accumulator chains (hi*hi, hi*lo, lo*hi)
    float16 a0, a1, a2;
#pragma unroll
    for (int q = 0; q < 16; ++q) { a0[q] = 0.0f; a1[q] = 0.0f; a2[q] = 0.0f; }

#pragma unroll
    for (int i = 0; i < MAXCH; ++i) {
      if (i < nch) {
        const int k2b = (clo + i) * 8 + half * 4;
        const unsigned* hp = &HB[k2b * STW + m];
        const unsigned* lp = &LB[k2b * STW + m];
        const uint4v hw = {hp[0], hp[32], hp[64], hp[96]};
        const uint4v lw = {lp[0], lp[32], lp[64], lp[96]};
        const bf16x8 bh = __builtin_bit_cast(bf16x8, hw);
        const bf16x8 bl = __builtin_bit_cast(bf16x8, lw);
        a0 = __builtin_amdgcn_mfma_f32_32x32x16_bf16(Ah[i], bh, a0, 0, 0, 0);
        a1 = __builtin_amdgcn_mfma_f32_32x32x16_bf16(Ah[i], bl, a1, 0, 0, 0);
        a2 = __builtin_amdgcn_mfma_f32_32x32x16_bf16(Al[i], bh, a2, 0, 0, 0);
      }
    }

    // epilogue: C/D map (32x32): col = lane&31, row = (r&3)+8*(r>>2)+4*half
    const int b  = tau / STILES_PER_B;
    const int s0 = (tau % STILES_PER_B) * STW;
    float* ob = out + (size_t)b * PER_B + (size_t)s0 + m;
#pragma unroll
    for (int r = 0; r < 16; ++r) {
      const int row = (r & 3) + 8 * (r >> 2) + 4 * half;
      ob[(size_t)(c0 + row) * SPATIAL] = a0[r] + a1[r] + a2[r];
    }
  }
}

extern "C" void kernel_launch(void* const* d_in, const int* in_sizes, int n_in,
                              void* d_out, int out_size, void* d_ws, size_t ws_size,
                              hipStream_t stream) {
  const float* x = (const float*)d_in[0];  // (32, 256, 56, 56) fp32
  const float* w = (const float*)d_in[1];  // (15,) fp32
  const int* ms = (const int*)d_in[2];     // scalar int (10)
  float* out = (float*)d_out;              // (32, 256, 56, 56) fp32

  unsigned short* Mh = (unsigned short*)d_ws;  // 128 KB
  unsigned short* Ml = Mh + NCH * NCH;         // 128 KB

  build_M_kernel<<<NCH, NCH, 0, stream>>>(w, ms, Mh, Ml);
  apply_M_kernel<<<GRID_APPLY, 512, 0, stream>>>(x, Mh, Ml, out);
}